// Round 5
// baseline (437.084 us; speedup 1.0000x reference)
//
#include <hip/hip_runtime.h>
#include <hip/hip_bf16.h>
#include <stdint.h>

#define B_ROWS 16384
#define D_IN   1200
#define D_PAD  1216      // 38 * 32
#define N_EXP  8
#define H_DIM  1024
#define CAP    33792     // 264 * 128 padded-row capacity
#define N_TILES 264
#define LN_EPS 1e-5f
#define GATE_EPS 1e-6f
#define CNT_STRIDE 16    // pad expert counters to separate 64B cache lines

// ---- workspace layout (bytes) ----
//   cnt   : [0, 512)
//   poff  : [512, 576)
//   cnt2  : [576, 1088)
//   topIdx: [1088, 132160)      16384*2 ints
//   topGate:[132160, 263232)    16384*2 floats
//   prowC : [263232, 398400)    33792 ints
//   pgateC: [398400, 533568)    33792 floats
//   xg    : [533568, 82715712)  33792*1216*2
//   w1t   : [82715712, 102638656) 8*1024*1216*2
//   hbuf  : [102638656, 171844672) 33792*1024*2   (~164 MB total)
#define O_CNT    0
#define O_POFF   512
#define O_CNT2   576
#define O_TOPI   1088
#define O_TOPG   132160
#define O_PROWC  263232
#define O_PGATEC 398400
#define O_XG     533568
#define O_W1T    82715712
#define O_HBUF   102638656

#define GATING_BLOCKS (B_ROWS / 4)        // 4096
#define W1T_BLOCKS    (38 * 32 * 8)       // 9728

typedef short bf16x8 __attribute__((ext_vector_type(8)));
typedef short short8 __attribute__((ext_vector_type(8)));
typedef short short4v __attribute__((ext_vector_type(4)));
typedef float f32x4 __attribute__((ext_vector_type(4)));

__device__ __forceinline__ void load_lds16(const void* gptr, void* ldsptr) {
    __builtin_amdgcn_global_load_lds(
        (__attribute__((address_space(1))) void*)const_cast<void*>(gptr),
        (__attribute__((address_space(3))) void*)ldsptr, 16, 0, 0);
}

__device__ __forceinline__ short8 pack_bf16x8(float4 a, float4 b) {
    union { short8 v; __hip_bfloat16 h[8]; } u;
    u.h[0] = __float2bfloat16(a.x); u.h[1] = __float2bfloat16(a.y);
    u.h[2] = __float2bfloat16(a.z); u.h[3] = __float2bfloat16(a.w);
    u.h[4] = __float2bfloat16(b.x); u.h[5] = __float2bfloat16(b.y);
    u.h[6] = __float2bfloat16(b.z); u.h[7] = __float2bfloat16(b.w);
    return u.v;
}

// ---------------- 1. fused gating (wave-per-row) + W1 transpose ----------------
// blocks [0, GATING_BLOCKS)                -> gating
// blocks [GATING_BLOCKS, +W1T_BLOCKS)      -> W1 [E][D][H] fp32 -> w1t [E][H][D_PAD] bf16
__global__ __launch_bounds__(256) void gating_w1t_kernel(
    const float* __restrict__ x, const float* __restrict__ wg,
    const float* __restrict__ W1,
    int* __restrict__ topIdx, float* __restrict__ topGate,
    __hip_bfloat16* __restrict__ w1t)
{
    __shared__ float tile[32][33];
    int bx = blockIdx.x;
    int tid = threadIdx.x;

    if (bx < GATING_BLOCKS) {
        int row = bx * 4 + (tid >> 6);
        int lane = tid & 63;
        const float4* xr = (const float4*)(x + (long)row * D_IN);   // 300 float4

        float acc[N_EXP];
#pragma unroll
        for (int e = 0; e < N_EXP; ++e) acc[e] = 0.f;

        for (int i = lane; i < 300; i += 64) {
            float4 xv = xr[i];
            const float4* w = (const float4*)(wg + (long)i * 32);   // 4 d-rows x 8 experts
            float4 w0 = w[0], w1 = w[1];
            float4 w2 = w[2], w3 = w[3];
            float4 w4 = w[4], w5 = w[5];
            float4 w6 = w[6], w7 = w[7];
            acc[0] += xv.x * w0.x + xv.y * w2.x + xv.z * w4.x + xv.w * w6.x;
            acc[1] += xv.x * w0.y + xv.y * w2.y + xv.z * w4.y + xv.w * w6.y;
            acc[2] += xv.x * w0.z + xv.y * w2.z + xv.z * w4.z + xv.w * w6.z;
            acc[3] += xv.x * w0.w + xv.y * w2.w + xv.z * w4.w + xv.w * w6.w;
            acc[4] += xv.x * w1.x + xv.y * w3.x + xv.z * w5.x + xv.w * w7.x;
            acc[5] += xv.x * w1.y + xv.y * w3.y + xv.z * w5.y + xv.w * w7.y;
            acc[6] += xv.x * w1.z + xv.y * w3.z + xv.z * w5.z + xv.w * w7.z;
            acc[7] += xv.x * w1.w + xv.y * w3.w + xv.z * w5.w + xv.w * w7.w;
        }

#pragma unroll
        for (int e = 0; e < N_EXP; ++e) {
            float v = acc[e];
#pragma unroll
            for (int off = 32; off > 0; off >>= 1) v += __shfl_xor(v, off, 64);
            acc[e] = v;
        }

        if (lane == 0) {
            float m = acc[0];
#pragma unroll
            for (int e = 1; e < N_EXP; ++e) m = fmaxf(m, acc[e]);
            float p[N_EXP], s = 0.f;
#pragma unroll
            for (int e = 0; e < N_EXP; ++e) { p[e] = expf(acc[e] - m); s += p[e]; }
            int i0 = 0;
#pragma unroll
            for (int e = 1; e < N_EXP; ++e) if (p[e] > p[i0]) i0 = e;
            int i1 = (i0 == 0) ? 1 : 0;
#pragma unroll
            for (int e = 0; e < N_EXP; ++e) if (e != i0 && p[e] > p[i1]) i1 = e;
            float v0 = p[i0] / s, v1 = p[i1] / s;
            float inv = 1.f / (v0 + v1 + GATE_EPS);
            ((int2*)topIdx)[row] = make_int2(i0, i1);
            ((float2*)topGate)[row] = make_float2(v0 * inv, v1 * inv);
        }
    } else {
        // ---- W1 transpose tile ----
        int b = bx - GATING_BLOCKS;          // [0, 9728)
        int d0 = (b % 38) * 32;
        int h0 = ((b / 38) % 32) * 32;
        int e = b / (38 * 32);
        int tx = tid & 31;
        int ty = tid >> 5;                   // 0..7
        const float* src = W1 + (long)e * D_IN * H_DIM;
#pragma unroll
        for (int s = 0; s < 4; ++s) {
            int d = d0 + ty + 8 * s;
            float v = (d < D_IN) ? src[(long)d * H_DIM + h0 + tx] : 0.f;
            tile[ty + 8 * s][tx] = v;
        }
        __syncthreads();
        __hip_bfloat16* dst = w1t + (long)e * H_DIM * D_PAD;
#pragma unroll
        for (int s = 0; s < 4; ++s) {
            int h = h0 + ty + 8 * s;
            dst[(long)h * D_PAD + d0 + tx] = __float2bfloat16(tile[tx][ty + 8 * s]);
        }
    }
}

// ---------------- 2. single-block histogram + prefix offsets ----------------
__global__ __launch_bounds__(256) void histoff_kernel(
    const int* __restrict__ topIdx, int* __restrict__ cnt, int* __restrict__ poff)
{
    __shared__ int sc[N_EXP];
    int tid = threadIdx.x;
    if (tid < N_EXP) sc[tid] = 0;
    __syncthreads();

    int lc[N_EXP];
#pragma unroll
    for (int e = 0; e < N_EXP; ++e) lc[e] = 0;
    for (int i = tid; i < 2 * B_ROWS; i += 256) {
        int ev = topIdx[i];
#pragma unroll
        for (int e = 0; e < N_EXP; ++e) lc[e] += (ev == e) ? 1 : 0;
    }
#pragma unroll
    for (int e = 0; e < N_EXP; ++e) {
        int v = lc[e];
#pragma unroll
        for (int off = 32; off > 0; off >>= 1) v += __shfl_xor(v, off, 64);
        if ((tid & 63) == 0) atomicAdd(&sc[e], v);
    }
    __syncthreads();
    if (tid == 0) {
        int o = 0;
        for (int e = 0; e < N_EXP; ++e) {
            cnt[e * CNT_STRIDE] = sc[e];
            poff[e] = o;
            o += (sc[e] + 127) & ~127;
        }
        poff[N_EXP] = o;
    }
}

// ---------------- 3. scatter rows into compact per-expert lists ----------------
__global__ __launch_bounds__(256) void scatter_kernel(
    const int* __restrict__ topIdx, const float* __restrict__ topGate,
    const int* __restrict__ poff, int* __restrict__ cnt2,
    int* __restrict__ pairRowC, float* __restrict__ pairGateC)
{
    __shared__ int lcnt[N_EXP];
    __shared__ int base[N_EXP];
    int tid = threadIdx.x;
    if (tid < N_EXP) lcnt[tid] = 0;
    __syncthreads();
    int row = blockIdx.x * 256 + tid;
    int2 e = ((const int2*)topIdx)[row];
    float2 g = ((const float2*)topGate)[row];
    int s0 = atomicAdd(&lcnt[e.x], 1);
    int s1 = atomicAdd(&lcnt[e.y], 1);
    __syncthreads();
    if (tid < N_EXP) base[tid] = atomicAdd(&cnt2[tid * CNT_STRIDE], lcnt[tid]);
    __syncthreads();
    int p0 = poff[e.x] + base[e.x] + s0;
    pairRowC[p0] = row; pairGateC[p0] = g.x;
    int p1 = poff[e.y] + base[e.y] + s1;
    pairRowC[p1] = row; pairGateC[p1] = g.y;
}

// ---------------- 4. gather selected rows into bf16 xg (vectorized 16B stores) ----------------
__global__ __launch_bounds__(192) void gather_kernel(
    const float* __restrict__ x, const int* __restrict__ cnt, const int* __restrict__ poff,
    const int* __restrict__ pairRowC, __hip_bfloat16* __restrict__ xg)
{
    int p = blockIdx.x;
    if (p >= poff[N_EXP]) return;
    int e = 0;
    while (e < N_EXP - 1 && p >= poff[e + 1]) ++e;
    int i = p - poff[e];
    int tid = threadIdx.x;
    short8* dst = (short8*)(xg + (long)p * D_PAD);   // 152 chunks of 8 bf16
    if (tid >= 152) return;

    if (i < cnt[e * CNT_STRIDE]) {
        int row = pairRowC[p];
        short8 out;
        if (tid < 150) {   // 150*8 = 1200 real elements
            const float4* src = (const float4*)(x + (long)row * D_IN) + tid * 2;
            out = pack_bf16x8(src[0], src[1]);
        } else {
            out = (short8){0,0,0,0,0,0,0,0};
        }
        dst[tid] = out;
    } else {
        dst[tid] = (short8){0,0,0,0,0,0,0,0};   // padding row: zero so GEMM is harmless
    }
}

// ---------------- 5. expert GEMM (round-3 grid order + XOR LDS swizzle) ----------------
__global__ __launch_bounds__(256) void gemm_kernel(
    const __hip_bfloat16* __restrict__ xg, const __hip_bfloat16* __restrict__ w1t,
    const float* __restrict__ b1, const int* __restrict__ poff,
    __hip_bfloat16* __restrict__ hbuf)
{
    // row-tile fastest (bx), col-tile outer (by): per col sweep each XCD keeps
    // 8 experts x 311 KB of B in its L2; A (xg) streams, L3-assisted.
    int row0 = blockIdx.x * 128;
    if (row0 >= poff[N_EXP]) return;
    int col0 = blockIdx.y * 128;
    int e = 0;
    while (e < N_EXP - 1 && row0 >= poff[e + 1]) ++e;

    __shared__ short lA[128 * 32];   // [row][4 segs of 8 bf16], seg XOR-swizzled by (row>>1)&3
    __shared__ short lB[128 * 32];

    int t = threadIdx.x;
    int lane = t & 63, w = t >> 6;
    int wm = (w >> 1) * 64, wn = (w & 1) * 64;
    int l15 = lane & 15, quad = lane >> 4;
    int qsw = quad ^ ((l15 >> 1) & 3);   // swizzled segment position at read time

    f32x4 acc[4][4];
#pragma unroll
    for (int i = 0; i < 4; ++i)
#pragma unroll
        for (int j = 0; j < 4; ++j) acc[i][j] = (f32x4){0.f, 0.f, 0.f, 0.f};

    const __hip_bfloat16* Ab = xg + (long)row0 * D_PAD;
    const __hip_bfloat16* Bb = w1t + (long)e * H_DIM * D_PAD + (long)col0 * D_PAD;

    // staging: thread t handles row r1 (and r1+64), k-segment seg; loads the
    // XOR-swizzled global segment so LDS[r][seg] = global chunk seg^((r>>1)&3).
    // (swizzle term for r1+64 equals that of r1 since 64 ≡ 0 mod 4 after >>1)
    int r1 = t >> 2, seg = t & 3;
    int sw = seg ^ ((r1 >> 1) & 3);
    long aoff1 = (long)r1 * D_PAD + sw * 8;
    long aoff2 = (long)(r1 + 64) * D_PAD + sw * 8;
    char* lAc = (char*)lA;
    char* lBc = (char*)lB;

    for (int kt = 0; kt < D_PAD / 32; ++kt) {
        __syncthreads();
        int k0 = kt * 32;
        load_lds16(Ab + aoff1 + k0, lAc + t * 16);
        load_lds16(Ab + aoff2 + k0, lAc + t * 16 + 4096);
        load_lds16(Bb + aoff1 + k0, lBc + t * 16);
        load_lds16(Bb + aoff2 + k0, lBc + t * 16 + 4096);
        __syncthreads();

        bf16x8 af[4], bfr[4];
#pragma unroll
        for (int i = 0; i < 4; ++i)
            af[i] = *(const bf16x8*)(lAc + (wm + i * 16 + l15) * 64 + qsw * 16);
#pragma unroll
        for (int j = 0; j < 4; ++j)
            bfr[j] = *(const bf16x8*)(lBc + (wn + j * 16 + l15) * 64 + qsw * 16);
#pragma unroll
        for (int i = 0; i < 4; ++i)
#pragma unroll
            for (int j = 0; j < 4; ++j)
                acc[i][j] = __builtin_amdgcn_mfma_f32_16x16x32_bf16(af[i], bfr[j], acc[i][j], 0, 0, 0);
    }

#pragma unroll
    for (int i = 0; i < 4; ++i) {
        int lr = wm + i * 16 + quad * 4;
#pragma unroll
        for (int j = 0; j < 4; ++j) {
            int gc = col0 + wn + j * 16 + l15;
            float bias = b1[e * H_DIM + gc];
#pragma unroll
            for (int r = 0; r < 4; ++r) {
                float v = acc[i][j][r] + bias;
                hbuf[(long)(row0 + lr + r) * H_DIM + gc] = __float2bfloat16(v);
            }
        }
    }
}

// ---------------- 6. LayerNorm + ReLU + head dot + sigmoid + gated combine ----------------
__global__ __launch_bounds__(256) void ln_head_kernel(
    const __hip_bfloat16* __restrict__ hbuf, const int* __restrict__ cnt, const int* __restrict__ poff,
    const int* __restrict__ pairRowC, const float* __restrict__ pairGateC,
    const float* __restrict__ g1, const float* __restrict__ be1,
    const float* __restrict__ W2, const float* __restrict__ b2,
    float* __restrict__ y)
{
    int p = blockIdx.x;
    if (p >= poff[N_EXP]) return;
    int e = 0;
    while (e < N_EXP - 1 && p >= poff[e + 1]) ++e;
    if (p - poff[e] >= cnt[e * CNT_STRIDE]) return;   // padding row

    int row = pairRowC[p];
    float gate = pairGateC[p];
    int tid = threadIdx.x;
    int w = tid >> 6;
    const __hip_bfloat16* hr = hbuf + (long)p * H_DIM;

    union { short4v s; __hip_bfloat16 h[4]; } hv;
    hv.s = ((const short4v*)hr)[tid];
    float v[4];
    float sum = 0.f, sumsq = 0.f;
#pragma unroll
    for (int k = 0; k < 4; ++k) {
        v[k] = __bfloat162float(hv.h[k]);
        sum += v[k];
        sumsq += v[k] * v[k];
    }
#pragma unroll
    for (int off = 32; off > 0; off >>= 1) {
        sum += __shfl_down(sum, off);
        sumsq += __shfl_down(sumsq, off);
    }
    __shared__ float rs[4], rq[4];
    if ((tid & 63) == 0) { rs[w] = sum; rq[w] = sumsq; }
    __syncthreads();
    float tot = rs[0] + rs[1] + rs[2] + rs[3];
    float totq = rq[0] + rq[1] + rq[2] + rq[3];
    float mu = tot * (1.f / H_DIM);
    float var = totq * (1.f / H_DIM) - mu * mu;
    float rstd = rsqrtf(var + LN_EPS);

    float4 gv = ((const float4*)(g1 + e * H_DIM))[tid];
    float4 bv = ((const float4*)(be1 + e * H_DIM))[tid];
    float4 wv = ((const float4*)(W2 + e * H_DIM))[tid];
    float z;
    {
        float hn0 = fmaxf((v[0] - mu) * rstd * gv.x + bv.x, 0.f);
        float hn1 = fmaxf((v[1] - mu) * rstd * gv.y + bv.y, 0.f);
        float hn2 = fmaxf((v[2] - mu) * rstd * gv.z + bv.z, 0.f);
        float hn3 = fmaxf((v[3] - mu) * rstd * gv.w + bv.w, 0.f);
        z = hn0 * wv.x + hn1 * wv.y + hn2 * wv.z + hn3 * wv.w;
    }
#pragma unroll
    for (int off = 32; off > 0; off >>= 1) z += __shfl_down(z, off);
    __syncthreads();
    if ((tid & 63) == 0) rs[w] = z;
    __syncthreads();
    if (tid == 0) {
        float zt = rs[0] + rs[1] + rs[2] + rs[3] + b2[e];
        float o = 1.f / (1.f + expf(-zt));
        atomicAdd(&y[row], gate * o);
    }
}

extern "C" void kernel_launch(void* const* d_in, const int* in_sizes, int n_in,
                              void* d_out, int out_size, void* d_ws, size_t ws_size,
                              hipStream_t stream)
{
    const float* x   = (const float*)d_in[0];
    const float* wg  = (const float*)d_in[1];
    const float* W1  = (const float*)d_in[2];
    const float* b1  = (const float*)d_in[3];
    const float* g1  = (const float*)d_in[4];
    const float* be1 = (const float*)d_in[5];
    const float* W2  = (const float*)d_in[6];
    const float* b2  = (const float*)d_in[7];
    float* y = (float*)d_out;

    char* ws = (char*)d_ws;
    int*   cnt       = (int*)(ws + O_CNT);
    int*   poff      = (int*)(ws + O_POFF);
    int*   cnt2      = (int*)(ws + O_CNT2);
    int*   topIdx    = (int*)(ws + O_TOPI);
    float* topGate   = (float*)(ws + O_TOPG);
    int*   pairRowC  = (int*)(ws + O_PROWC);
    float* pairGateC = (float*)(ws + O_PGATEC);
    __hip_bfloat16* xg   = (__hip_bfloat16*)(ws + O_XG);
    __hip_bfloat16* w1t  = (__hip_bfloat16*)(ws + O_W1T);
    __hip_bfloat16* hbuf = (__hip_bfloat16*)(ws + O_HBUF);

    hipMemsetAsync(ws, 0, 1088, stream);   // cnt + poff + cnt2 in one shot
    hipMemsetAsync(y, 0, (size_t)out_size * sizeof(float), stream);

    gating_w1t_kernel<<<GATING_BLOCKS + W1T_BLOCKS, 256, 0, stream>>>(
        x, wg, W1, topIdx, topGate, w1t);
    histoff_kernel<<<1, 256, 0, stream>>>(topIdx, cnt, poff);
    scatter_kernel<<<B_ROWS / 256, 256, 0, stream>>>(topIdx, topGate, poff, cnt2,
                                                     pairRowC, pairGateC);
    gather_kernel<<<CAP, 192, 0, stream>>>(x, cnt, poff, pairRowC, xg);
    gemm_kernel<<<dim3(N_TILES, 8), 256, 0, stream>>>(xg, w1t, b1, poff, hbuf);
    ln_head_kernel<<<CAP, 256, 0, stream>>>(hbuf, cnt, poff, pairRowC, pairGateC,
                                            g1, be1, W2, b2, y);
}

// Round 6
// 373.352 us; speedup vs baseline: 1.1707x; 1.1707x over previous
//
#include <hip/hip_runtime.h>
#include <hip/hip_bf16.h>
#include <stdint.h>

#define B_ROWS 16384
#define D_IN   1200
#define D_PAD  1216      // 38 * 32
#define N_EXP  8
#define H_DIM  1024
#define CAP    33792     // 264 * 128 padded-row capacity
#define N_TILES 264
#define LN_EPS 1e-5f
#define GATE_EPS 1e-6f
#define CNT_STRIDE 16    // pad expert counters to separate 64B cache lines

// ---- workspace layout (bytes) ----
//   cnt   : [0, 512)
//   poff  : [512, 576)
//   cnt2  : [576, 1088)
//   topIdx: [1088, 132160)        16384*2 ints
//   topGate:[132160, 263232)      16384*2 floats
//   prowC : [263232, 398400)      33792 ints
//   pgateC: [398400, 533568)      33792 floats
//   xbf   : [533568, 40381888)    16385*1216*2  (row 16384 = zeros for padding)
//   w1t   : [40381888, 60304832)  8*1024*1216*2
//   hbuf  : [60304832, 129510848) 33792*1024*2   (~124 MB total)
#define O_CNT    0
#define O_POFF   512
#define O_CNT2   576
#define O_TOPI   1088
#define O_TOPG   132160
#define O_PROWC  263232
#define O_PGATEC 398400
#define O_XBF    533568
#define O_W1T    40381888
#define O_HBUF   60304832

#define GATING_BLOCKS (B_ROWS / 4)        // 4096
#define W1T_BLOCKS    (38 * 32 * 8)       // 9728

typedef short bf16x8 __attribute__((ext_vector_type(8)));
typedef short short8 __attribute__((ext_vector_type(8)));
typedef short short4v __attribute__((ext_vector_type(4)));
typedef float f32x4 __attribute__((ext_vector_type(4)));

__device__ __forceinline__ void load_lds16(const void* gptr, void* ldsptr) {
    __builtin_amdgcn_global_load_lds(
        (__attribute__((address_space(1))) void*)const_cast<void*>(gptr),
        (__attribute__((address_space(3))) void*)ldsptr, 16, 0, 0);
}

__device__ __forceinline__ short8 pack_bf16x8(float4 a, float4 b) {
    union { short8 v; __hip_bfloat16 h[8]; } u;
    u.h[0] = __float2bfloat16(a.x); u.h[1] = __float2bfloat16(a.y);
    u.h[2] = __float2bfloat16(a.z); u.h[3] = __float2bfloat16(a.w);
    u.h[4] = __float2bfloat16(b.x); u.h[5] = __float2bfloat16(b.y);
    u.h[6] = __float2bfloat16(b.z); u.h[7] = __float2bfloat16(b.w);
    return u.v;
}

// ---------------- 1. fused: gating (wave-per-row) + x->bf16 + W1 transpose ----------------
// blocks [0, GATING_BLOCKS)           -> gating + xbf write (4 rows/block)
// block  GATING_BLOCKS                -> zero xbf row 16384 (padding row)
// blocks (GATING_BLOCKS, +W1T_BLOCKS] -> W1 [E][D][H] fp32 -> w1t [E][H][D_PAD] bf16
__global__ __launch_bounds__(256) void gating_w1t_kernel(
    const float* __restrict__ x, const float* __restrict__ wg,
    const float* __restrict__ W1,
    int* __restrict__ topIdx, float* __restrict__ topGate,
    __hip_bfloat16* __restrict__ w1t, __hip_bfloat16* __restrict__ xbf)
{
    __shared__ float tile[32][33];
    int bx = blockIdx.x;
    int tid = threadIdx.x;

    if (bx < GATING_BLOCKS) {
        int row = bx * 4 + (tid >> 6);
        int lane = tid & 63;
        const float4* xr = (const float4*)(x + (long)row * D_IN);   // 300 float4

        float acc[N_EXP];
#pragma unroll
        for (int e = 0; e < N_EXP; ++e) acc[e] = 0.f;

        for (int i = lane; i < 300; i += 64) {
            float4 xv = xr[i];
            const float4* w = (const float4*)(wg + (long)i * 32);   // 4 d-rows x 8 experts
            float4 w0 = w[0], w1 = w[1];
            float4 w2 = w[2], w3 = w[3];
            float4 w4 = w[4], w5 = w[5];
            float4 w6 = w[6], w7 = w[7];
            acc[0] += xv.x * w0.x + xv.y * w2.x + xv.z * w4.x + xv.w * w6.x;
            acc[1] += xv.x * w0.y + xv.y * w2.y + xv.z * w4.y + xv.w * w6.y;
            acc[2] += xv.x * w0.z + xv.y * w2.z + xv.z * w4.z + xv.w * w6.z;
            acc[3] += xv.x * w0.w + xv.y * w2.w + xv.z * w4.w + xv.w * w6.w;
            acc[4] += xv.x * w1.x + xv.y * w3.x + xv.z * w5.x + xv.w * w7.x;
            acc[5] += xv.x * w1.y + xv.y * w3.y + xv.z * w5.y + xv.w * w7.y;
            acc[6] += xv.x * w1.z + xv.y * w3.z + xv.z * w5.z + xv.w * w7.z;
            acc[7] += xv.x * w1.w + xv.y * w3.w + xv.z * w5.w + xv.w * w7.w;
        }

        // bf16 copy of this row (reads are L1/L2-hot from the loop above)
        short8* xrow = (short8*)(xbf + (long)row * D_PAD);
        for (int i = lane; i < 152; i += 64) {
            short8 out;
            if (i < 150) out = pack_bf16x8(xr[2 * i], xr[2 * i + 1]);
            else         out = (short8){0,0,0,0,0,0,0,0};
            xrow[i] = out;
        }

#pragma unroll
        for (int e = 0; e < N_EXP; ++e) {
            float v = acc[e];
#pragma unroll
            for (int off = 32; off > 0; off >>= 1) v += __shfl_xor(v, off, 64);
            acc[e] = v;
        }

        if (lane == 0) {
            float m = acc[0];
#pragma unroll
            for (int e = 1; e < N_EXP; ++e) m = fmaxf(m, acc[e]);
            float p[N_EXP], s = 0.f;
#pragma unroll
            for (int e = 0; e < N_EXP; ++e) { p[e] = expf(acc[e] - m); s += p[e]; }
            int i0 = 0;
#pragma unroll
            for (int e = 1; e < N_EXP; ++e) if (p[e] > p[i0]) i0 = e;
            int i1 = (i0 == 0) ? 1 : 0;
#pragma unroll
            for (int e = 0; e < N_EXP; ++e) if (e != i0 && p[e] > p[i1]) i1 = e;
            float v0 = p[i0] / s, v1 = p[i1] / s;
            float inv = 1.f / (v0 + v1 + GATE_EPS);
            ((int2*)topIdx)[row] = make_int2(i0, i1);
            ((float2*)topGate)[row] = make_float2(v0 * inv, v1 * inv);
        }
    } else if (bx == GATING_BLOCKS) {
        // zero the padding row of xbf
        short8* xrow = (short8*)(xbf + (long)B_ROWS * D_PAD);
        if (tid < 152) xrow[tid] = (short8){0,0,0,0,0,0,0,0};
    } else {
        // ---- W1 transpose tile ----
        int b = bx - GATING_BLOCKS - 1;      // [0, 9728)
        int d0 = (b % 38) * 32;
        int h0 = ((b / 38) % 32) * 32;
        int e = b / (38 * 32);
        int tx = tid & 31;
        int ty = tid >> 5;                   // 0..7
        const float* src = W1 + (long)e * D_IN * H_DIM;
#pragma unroll
        for (int s = 0; s < 4; ++s) {
            int d = d0 + ty + 8 * s;
            float v = (d < D_IN) ? src[(long)d * H_DIM + h0 + tx] : 0.f;
            tile[ty + 8 * s][tx] = v;
        }
        __syncthreads();
        __hip_bfloat16* dst = w1t + (long)e * H_DIM * D_PAD;
#pragma unroll
        for (int s = 0; s < 4; ++s) {
            int h = h0 + ty + 8 * s;
            dst[(long)h * D_PAD + d0 + tx] = __float2bfloat16(tile[tx][ty + 8 * s]);
        }
    }
}

// ---------------- 2a. histogram: LDS-aggregated, 8 padded global atomics/block ----------------
__global__ __launch_bounds__(256) void hist_kernel(
    const int* __restrict__ topIdx, int* __restrict__ cnt)
{
    __shared__ int lcnt[N_EXP];
    int tid = threadIdx.x;
    if (tid < N_EXP) lcnt[tid] = 0;
    __syncthreads();
    int row = blockIdx.x * 256 + tid;
    int2 e = ((const int2*)topIdx)[row];
    atomicAdd(&lcnt[e.x], 1);
    atomicAdd(&lcnt[e.y], 1);
    __syncthreads();
    if (tid < N_EXP) atomicAdd(&cnt[tid * CNT_STRIDE], lcnt[tid]);
}

// ---------------- 2b. prefix sum to 128-padded per-expert offsets ----------------
__global__ void offsets_kernel(const int* __restrict__ cnt, int* __restrict__ poff)
{
    if (threadIdx.x == 0 && blockIdx.x == 0) {
        int o = 0;
        for (int e = 0; e < N_EXP; ++e) {
            poff[e] = o;
            o += (cnt[e * CNT_STRIDE] + 127) & ~127;
        }
        poff[N_EXP] = o;
    }
}

// ---------------- 3. scatter rows into compact per-expert lists + pad-slot init ----------------
__global__ __launch_bounds__(256) void scatter_kernel(
    const int* __restrict__ topIdx, const float* __restrict__ topGate,
    const int* __restrict__ cnt, const int* __restrict__ poff, int* __restrict__ cnt2,
    int* __restrict__ pairRowC, float* __restrict__ pairGateC)
{
    int tid = threadIdx.x;
    int b = blockIdx.x;

    // pad-slot init (all 132 blocks cover all CAP slots; padding & real slots disjoint)
    {
        int p = b * 256 + tid;
        int e = 0;
        while (e < N_EXP - 1 && p >= poff[e + 1]) ++e;
        if (p - poff[e] >= cnt[e * CNT_STRIDE]) {
            pairRowC[p] = B_ROWS;      // points at the zero row of xbf
            pairGateC[p] = 0.f;
        }
    }
    if (b >= B_ROWS / 256) return;

    __shared__ int lcnt[N_EXP];
    __shared__ int base[N_EXP];
    if (tid < N_EXP) lcnt[tid] = 0;
    __syncthreads();
    int row = b * 256 + tid;
    int2 e = ((const int2*)topIdx)[row];
    float2 g = ((const float2*)topGate)[row];
    int s0 = atomicAdd(&lcnt[e.x], 1);
    int s1 = atomicAdd(&lcnt[e.y], 1);
    __syncthreads();
    if (tid < N_EXP) base[tid] = atomicAdd(&cnt2[tid * CNT_STRIDE], lcnt[tid]);
    __syncthreads();
    int p0 = poff[e.x] + base[e.x] + s0;
    pairRowC[p0] = row; pairGateC[p0] = g.x;
    int p1 = poff[e.y] + base[e.y] + s1;
    pairRowC[p1] = row; pairGateC[p1] = g.y;
}

// ---------------- 4. expert GEMM: A indirect from xbf, XCD-aware tile mapping ----------------
__global__ __launch_bounds__(256) void gemm_kernel(
    const __hip_bfloat16* __restrict__ xbf, const __hip_bfloat16* __restrict__ w1t,
    const float* __restrict__ b1, const int* __restrict__ poff,
    const int* __restrict__ pairRowC,
    __hip_bfloat16* __restrict__ hbuf)
{
    // dispatch round-robins blocks over 8 XCDs (blockIdx % 8). Give XCD k row
    // tiles [33k, 33k+33), col fastest: A row-tile (311 KB) and the expert's B
    // (2.5 MB) stay XCD-L2-resident; A is fetched from HBM exactly once.
    int bi = blockIdx.x;
    int xcd = bi & 7;
    int j = bi >> 3;                 // [0, 264)
    int col0 = (j & 7) << 7;
    int rt = xcd * 33 + (j >> 3);    // [0, 264)
    int row0 = rt << 7;
    if (row0 >= poff[N_EXP]) return;
    int e = 0;
    while (e < N_EXP - 1 && row0 >= poff[e + 1]) ++e;

    __shared__ short lA[128 * 32];   // [row][4 segs of 8 bf16], seg XOR-swizzled by (row>>1)&3
    __shared__ short lB[128 * 32];

    int t = threadIdx.x;
    int lane = t & 63, w = t >> 6;
    int wm = (w >> 1) * 64, wn = (w & 1) * 64;
    int l15 = lane & 15, quad = lane >> 4;
    int qsw = quad ^ ((l15 >> 1) & 3);   // swizzled segment position at read time

    f32x4 acc[4][4];
#pragma unroll
    for (int i = 0; i < 4; ++i)
#pragma unroll
        for (int j2 = 0; j2 < 4; ++j2) acc[i][j2] = (f32x4){0.f, 0.f, 0.f, 0.f};

    // staging: thread t handles tile-rows r1 / r1+64, k-segment seg; global side
    // of global_load_lds is per-lane (indirect rows OK); LDS side stays t*16.
    int r1 = t >> 2, seg = t & 3;
    int sw = seg ^ ((r1 >> 1) & 3);
    int ridx1 = pairRowC[row0 + r1];
    int ridx2 = pairRowC[row0 + 64 + r1];
    const __hip_bfloat16* Arow1 = xbf + (long)ridx1 * D_PAD + sw * 8;
    const __hip_bfloat16* Arow2 = xbf + (long)ridx2 * D_PAD + sw * 8;
    const __hip_bfloat16* Bb = w1t + (long)e * H_DIM * D_PAD + (long)col0 * D_PAD;
    const __hip_bfloat16* Brow1 = Bb + (long)r1 * D_PAD + sw * 8;
    const __hip_bfloat16* Brow2 = Bb + (long)(r1 + 64) * D_PAD + sw * 8;
    char* lAc = (char*)lA;
    char* lBc = (char*)lB;

    for (int kt = 0; kt < D_PAD / 32; ++kt) {
        __syncthreads();
        int k0 = kt * 32;
        load_lds16(Arow1 + k0, lAc + t * 16);
        load_lds16(Arow2 + k0, lAc + t * 16 + 4096);
        load_lds16(Brow1 + k0, lBc + t * 16);
        load_lds16(Brow2 + k0, lBc + t * 16 + 4096);
        __syncthreads();

        bf16x8 af[4], bfr[4];
#pragma unroll
        for (int i = 0; i < 4; ++i)
            af[i] = *(const bf16x8*)(lAc + (wm + i * 16 + l15) * 64 + qsw * 16);
#pragma unroll
        for (int j2 = 0; j2 < 4; ++j2)
            bfr[j2] = *(const bf16x8*)(lBc + (wn + j2 * 16 + l15) * 64 + qsw * 16);
#pragma unroll
        for (int i = 0; i < 4; ++i)
#pragma unroll
            for (int j2 = 0; j2 < 4; ++j2)
                acc[i][j2] = __builtin_amdgcn_mfma_f32_16x16x32_bf16(af[i], bfr[j2], acc[i][j2], 0, 0, 0);
    }

#pragma unroll
    for (int i = 0; i < 4; ++i) {
        int lr = wm + i * 16 + quad * 4;
#pragma unroll
        for (int j2 = 0; j2 < 4; ++j2) {
            int gc = col0 + wn + j2 * 16 + l15;
            float bias = b1[e * H_DIM + gc];
#pragma unroll
            for (int r = 0; r < 4; ++r) {
                float v = acc[i][j2][r] + bias;
                hbuf[(long)(row0 + lr + r) * H_DIM + gc] = __float2bfloat16(v);
            }
        }
    }
}

// ---------------- 5. LayerNorm + ReLU + head dot + sigmoid + gated combine ----------------
__global__ __launch_bounds__(256) void ln_head_kernel(
    const __hip_bfloat16* __restrict__ hbuf, const int* __restrict__ cnt, const int* __restrict__ poff,
    const int* __restrict__ pairRowC, const float* __restrict__ pairGateC,
    const float* __restrict__ g1, const float* __restrict__ be1,
    const float* __restrict__ W2, const float* __restrict__ b2,
    float* __restrict__ y)
{
    int p = blockIdx.x;
    if (p >= poff[N_EXP]) return;
    int e = 0;
    while (e < N_EXP - 1 && p >= poff[e + 1]) ++e;
    if (p - poff[e] >= cnt[e * CNT_STRIDE]) return;   // padding row

    int row = pairRowC[p];
    float gate = pairGateC[p];
    int tid = threadIdx.x;
    int w = tid >> 6;
    const __hip_bfloat16* hr = hbuf + (long)p * H_DIM;

    union { short4v s; __hip_bfloat16 h[4]; } hv;
    hv.s = ((const short4v*)hr)[tid];
    float v[4];
    float sum = 0.f, sumsq = 0.f;
#pragma unroll
    for (int k = 0; k < 4; ++k) {
        v[k] = __bfloat162float(hv.h[k]);
        sum += v[k];
        sumsq += v[k] * v[k];
    }
#pragma unroll
    for (int off = 32; off > 0; off >>= 1) {
        sum += __shfl_down(sum, off);
        sumsq += __shfl_down(sumsq, off);
    }
    __shared__ float rs[4], rq[4];
    if ((tid & 63) == 0) { rs[w] = sum; rq[w] = sumsq; }
    __syncthreads();
    float tot = rs[0] + rs[1] + rs[2] + rs[3];
    float totq = rq[0] + rq[1] + rq[2] + rq[3];
    float mu = tot * (1.f / H_DIM);
    float var = totq * (1.f / H_DIM) - mu * mu;
    float rstd = rsqrtf(var + LN_EPS);

    float4 gv = ((const float4*)(g1 + e * H_DIM))[tid];
    float4 bv = ((const float4*)(be1 + e * H_DIM))[tid];
    float4 wv = ((const float4*)(W2 + e * H_DIM))[tid];
    float z;
    {
        float hn0 = fmaxf((v[0] - mu) * rstd * gv.x + bv.x, 0.f);
        float hn1 = fmaxf((v[1] - mu) * rstd * gv.y + bv.y, 0.f);
        float hn2 = fmaxf((v[2] - mu) * rstd * gv.z + bv.z, 0.f);
        float hn3 = fmaxf((v[3] - mu) * rstd * gv.w + bv.w, 0.f);
        z = hn0 * wv.x + hn1 * wv.y + hn2 * wv.z + hn3 * wv.w;
    }
#pragma unroll
    for (int off = 32; off > 0; off >>= 1) z += __shfl_down(z, off);
    __syncthreads();
    if ((tid & 63) == 0) rs[w] = z;
    __syncthreads();
    if (tid == 0) {
        float zt = rs[0] + rs[1] + rs[2] + rs[3] + b2[e];
        float o = 1.f / (1.f + expf(-zt));
        atomicAdd(&y[row], gate * o);
    }
}

extern "C" void kernel_launch(void* const* d_in, const int* in_sizes, int n_in,
                              void* d_out, int out_size, void* d_ws, size_t ws_size,
                              hipStream_t stream)
{
    const float* x   = (const float*)d_in[0];
    const float* wg  = (const float*)d_in[1];
    const float* W1  = (const float*)d_in[2];
    const float* b1  = (const float*)d_in[3];
    const float* g1  = (const float*)d_in[4];
    const float* be1 = (const float*)d_in[5];
    const float* W2  = (const float*)d_in[6];
    const float* b2  = (const float*)d_in[7];
    float* y = (float*)d_out;

    char* ws = (char*)d_ws;
    int*   cnt       = (int*)(ws + O_CNT);
    int*   poff      = (int*)(ws + O_POFF);
    int*   cnt2      = (int*)(ws + O_CNT2);
    int*   topIdx    = (int*)(ws + O_TOPI);
    float* topGate   = (float*)(ws + O_TOPG);
    int*   pairRowC  = (int*)(ws + O_PROWC);
    float* pairGateC = (float*)(ws + O_PGATEC);
    __hip_bfloat16* xbf  = (__hip_bfloat16*)(ws + O_XBF);
    __hip_bfloat16* w1t  = (__hip_bfloat16*)(ws + O_W1T);
    __hip_bfloat16* hbuf = (__hip_bfloat16*)(ws + O_HBUF);

    hipMemsetAsync(ws, 0, 1088, stream);   // cnt + poff + cnt2
    hipMemsetAsync(y, 0, (size_t)out_size * sizeof(float), stream);

    gating_w1t_kernel<<<GATING_BLOCKS + 1 + W1T_BLOCKS, 256, 0, stream>>>(
        x, wg, W1, topIdx, topGate, w1t, xbf);
    hist_kernel<<<B_ROWS / 256, 256, 0, stream>>>(topIdx, cnt);
    offsets_kernel<<<1, 64, 0, stream>>>(cnt, poff);
    scatter_kernel<<<CAP / 256, 256, 0, stream>>>(topIdx, topGate, cnt, poff, cnt2,
                                                  pairRowC, pairGateC);
    gemm_kernel<<<N_TILES * 8, 256, 0, stream>>>(xbf, w1t, b1, poff, pairRowC, hbuf);
    ln_head_kernel<<<CAP, 256, 0, stream>>>(hbuf, cnt, poff, pairRowC, pairGateC,
                                            g1, be1, W2, b2, y);
}

// Round 7
// 312.822 us; speedup vs baseline: 1.3972x; 1.1935x over previous
//
#include <hip/hip_runtime.h>
#include <hip/hip_bf16.h>
#include <stdint.h>

#define B_ROWS 16384
#define D_IN   1200
#define D_PAD  1216      // 38 * 32
#define N_EXP  8
#define H_DIM  1024
#define CAP    33792     // 264 * 128 padded-row capacity
#define N_TILES 264
#define LN_EPS 1e-5f
#define GATE_EPS 1e-6f
#define CNT_STRIDE 16    // pad expert counters to separate 64B cache lines

// ---- workspace layout (bytes) ----
#define O_CNT    0
#define O_POFF   512
#define O_CNT2   576
#define O_TOPI   1088
#define O_TOPG   132160
#define O_PROWC  263232
#define O_PGATEC 398400
#define O_XBF    533568      // 16385*1216*2 (row 16384 = zeros for padding)
#define O_W1T    40381888    // 8*1024*1216*2
#define O_HBUF   60304832    // 33792*1024*2  (~124 MB total)

#define GATING_BLOCKS (B_ROWS / 32)       // 512 (8 rows/wave, 4 waves)
#define W1T_BLOCKS    (19 * 16 * 8)       // 2432  (64d x 64h tiles)

typedef short bf16x8 __attribute__((ext_vector_type(8)));
typedef short short8 __attribute__((ext_vector_type(8)));
typedef short short4v __attribute__((ext_vector_type(4)));
typedef float f32x4 __attribute__((ext_vector_type(4)));

__device__ __forceinline__ void load_lds16(const void* gptr, void* ldsptr) {
    __builtin_amdgcn_global_load_lds(
        (__attribute__((address_space(1))) void*)const_cast<void*>(gptr),
        (__attribute__((address_space(3))) void*)ldsptr, 16, 0, 0);
}

__device__ __forceinline__ short4v pack_bf16x4(float4 a) {
    union { short4v v; __hip_bfloat16 h[4]; } u;
    u.h[0] = __float2bfloat16(a.x); u.h[1] = __float2bfloat16(a.y);
    u.h[2] = __float2bfloat16(a.z); u.h[3] = __float2bfloat16(a.w);
    return u.v;
}

// ---------------- 1. fused: gating (8 rows/wave) + x->bf16 + W1 transpose ----------------
// blocks [0, GATING_BLOCKS)           -> gating + xbf write (32 rows/block)
// block  GATING_BLOCKS                -> zero xbf row 16384 (padding row)
// blocks (GATING_BLOCKS, +W1T_BLOCKS] -> W1 [E][D][H] fp32 -> w1t [E][H][D_PAD] bf16
__global__ __launch_bounds__(256) void gating_w1t_kernel(
    const float* __restrict__ x, const float* __restrict__ wg,
    const float* __restrict__ W1,
    int* __restrict__ topIdx, float* __restrict__ topGate,
    __hip_bfloat16* __restrict__ w1t, __hip_bfloat16* __restrict__ xbf)
{
    __shared__ float tile[2][32][33];   // two 32x32 fp32 tiles (w1t path)
    int bx = blockIdx.x;
    int tid = threadIdx.x;

    if (bx < GATING_BLOCKS) {
        int widx = tid >> 6;
        int lane = tid & 63;
        int rowbase = bx * 32 + widx * 8;
        const float* xw = x + (long)rowbase * D_IN;

        float acc[8][8];
#pragma unroll
        for (int r = 0; r < 8; ++r)
#pragma unroll
            for (int e = 0; e < N_EXP; ++e) acc[r][e] = 0.f;

        for (int i = lane; i < 304; i += 64) {
            if (i < 300) {
                const float4* wv4 = (const float4*)(wg + (long)i * 32);
                float4 w0 = wv4[0], w1v = wv4[1], w2 = wv4[2], w3 = wv4[3],
                       w4 = wv4[4], w5 = wv4[5], w6 = wv4[6], w7 = wv4[7];
#pragma unroll
                for (int r = 0; r < 8; ++r) {
                    float4 xv = ((const float4*)(xw + (long)r * D_IN))[i];
                    acc[r][0] += xv.x * w0.x + xv.y * w2.x + xv.z * w4.x + xv.w * w6.x;
                    acc[r][1] += xv.x * w0.y + xv.y * w2.y + xv.z * w4.y + xv.w * w6.y;
                    acc[r][2] += xv.x * w0.z + xv.y * w2.z + xv.z * w4.z + xv.w * w6.z;
                    acc[r][3] += xv.x * w0.w + xv.y * w2.w + xv.z * w4.w + xv.w * w6.w;
                    acc[r][4] += xv.x * w1v.x + xv.y * w3.x + xv.z * w5.x + xv.w * w7.x;
                    acc[r][5] += xv.x * w1v.y + xv.y * w3.y + xv.z * w5.y + xv.w * w7.y;
                    acc[r][6] += xv.x * w1v.z + xv.y * w3.z + xv.z * w5.z + xv.w * w7.z;
                    acc[r][7] += xv.x * w1v.w + xv.y * w3.w + xv.z * w5.w + xv.w * w7.w;
                    ((short4v*)(xbf + (long)(rowbase + r) * D_PAD))[i] = pack_bf16x4(xv);
                }
            } else {
#pragma unroll
                for (int r = 0; r < 8; ++r)
                    ((short4v*)(xbf + (long)(rowbase + r) * D_PAD))[i] = (short4v){0, 0, 0, 0};
            }
        }

        // full 64-lane butterfly: every lane ends with every row's totals
#pragma unroll
        for (int r = 0; r < 8; ++r)
#pragma unroll
            for (int e = 0; e < N_EXP; ++e) {
                float v = acc[r][e];
#pragma unroll
                for (int off = 32; off > 0; off >>= 1) v += __shfl_xor(v, off, 64);
                acc[r][e] = v;
            }

        // lane r (r<8) takes row r's totals via cndmask chain (no dynamic reg index)
        float my[N_EXP];
#pragma unroll
        for (int e = 0; e < N_EXP; ++e) my[e] = acc[0][e];
#pragma unroll
        for (int r = 1; r < 8; ++r)
#pragma unroll
            for (int e = 0; e < N_EXP; ++e)
                if (lane == r) my[e] = acc[r][e];

        if (lane < 8) {
            float m = my[0];
#pragma unroll
            for (int e = 1; e < N_EXP; ++e) m = fmaxf(m, my[e]);
            float p[N_EXP], s = 0.f;
#pragma unroll
            for (int e = 0; e < N_EXP; ++e) { p[e] = expf(my[e] - m); s += p[e]; }
            int i0 = 0;
#pragma unroll
            for (int e = 1; e < N_EXP; ++e) if (p[e] > p[i0]) i0 = e;
            int i1 = (i0 == 0) ? 1 : 0;
#pragma unroll
            for (int e = 0; e < N_EXP; ++e) if (e != i0 && p[e] > p[i1]) i1 = e;
            float v0 = p[i0] / s, v1 = p[i1] / s;
            float inv = 1.f / (v0 + v1 + GATE_EPS);
            int row = rowbase + lane;
            ((int2*)topIdx)[row] = make_int2(i0, i1);
            ((float2*)topGate)[row] = make_float2(v0 * inv, v1 * inv);
        }
    } else if (bx == GATING_BLOCKS) {
        short8* xrow = (short8*)(xbf + (long)B_ROWS * D_PAD);
        if (tid < 152) xrow[tid] = (short8){0, 0, 0, 0, 0, 0, 0, 0};
    } else {
        // ---- W1 transpose: 64d x 64h per block as two 32x32 tiles ----
        int b = bx - GATING_BLOCKS - 1;        // [0, 2432)
        int d0 = (b % 19) * 64;
        int h0 = ((b / 19) % 16) * 64;
        int e = b / (19 * 16);
        const float* src = W1 + (long)e * D_IN * H_DIM;

        // phase 1: load 64x64 fp32 (two 32-d tiles), h contiguous float4
        int hseg = tid & 7;          // float4 index within 32-h tile? no: 64h = 16 float4
        // remap: 64 h per d-row = 16 float4; 256 threads = 16 d-rows x 16 h-segs
        int hs = tid & 15;           // 0..15 -> h offset hs*4
        int dr = tid >> 4;           // 0..15
        (void)hseg;
#pragma unroll
        for (int s = 0; s < 4; ++s) {
            int dl = dr + 16 * s;    // 0..63
            int d = d0 + dl;
            float4 v = (d < D_IN)
                ? ((const float4*)(src + (long)d * H_DIM + h0))[hs]
                : (float4){0.f, 0.f, 0.f, 0.f};
            int T = dl >> 5, drl = dl & 31;
            int hl = hs * 4;         // 0..60 ; but tile is 32 h wide -> split
            // tile[T][drl][h'] holds h' = 0..31 => h = h0 + (hs<16? ...)
            // h index: hs*4 + j spans 0..63; tile h-dim is 32 -> use two h halves:
            int Th = hl >> 5;        // 0 or 1: which 32-h half
            int hh = hl & 31;
            // store into tile[(T)][drl][hh] for half Th -> fold Th into T? T in {0,1}, Th in {0,1}
            // we have 2 tiles of [32d][32h] but need 4 quadrants; process h-halves sequentially:
            // write both halves into the same 2 tiles is wrong -> instead treat tile dim0 as h-half
            // Simplification: tile[Th][drl within 32? no, d spans 64]...
            // ---- use layout: tile[Th][d_low 32][33] and handle d-halves sequentially ----
            (void)T; (void)hh;
            tile[Th][drl][hh + 0] = v.x;   // only valid when dl < 32 (first d-half)
            tile[Th][drl][hh + 1] = v.y;
            tile[Th][drl][hh + 2] = v.z;
            tile[Th][drl][hh + 3] = v.w;
            if (s == 1) {            // after d-rows 0..31 staged, drain first d-half
                __syncthreads();
                // phase 2a: write d-half 0: 64 h rows x 32 d
                int r2 = tid;        // 256 threads: T2 = r2>>7 (h-half), rr = r2&127
                int T2 = r2 >> 7, rr = r2 & 127;
                int hl2 = rr >> 2, dseg = rr & 3;
                float f[8];
#pragma unroll
                for (int j = 0; j < 8; ++j) f[j] = tile[T2][dseg * 8 + j][hl2];
                union { short8 v8; __hip_bfloat16 hh8[8]; } u;
#pragma unroll
                for (int j = 0; j < 8; ++j) u.hh8[j] = __float2bfloat16(f[j]);
                int h = h0 + T2 * 32 + hl2;
                ((short8*)(w1t + (long)e * H_DIM * D_PAD + (long)h * D_PAD + d0))[dseg] = u.v8;
                __syncthreads();
            }
        }
        __syncthreads();
        // phase 2b: write d-half 1 (d-rows 32..63 now in tiles)
        {
            int T2 = tid >> 7, rr = tid & 127;
            int hl2 = rr >> 2, dseg = rr & 3;
            float f[8];
#pragma unroll
            for (int j = 0; j < 8; ++j) f[j] = tile[T2][dseg * 8 + j][hl2];
            union { short8 v8; __hip_bfloat16 hh8[8]; } u;
#pragma unroll
            for (int j = 0; j < 8; ++j) u.hh8[j] = __float2bfloat16(f[j]);
            int h = h0 + T2 * 32 + hl2;
            ((short8*)(w1t + (long)e * H_DIM * D_PAD + (long)h * D_PAD + d0 + 32))[dseg] = u.v8;
        }
    }
}

// ---------------- 2a. histogram + y zero: LDS-aggregated, 8 padded atomics/block ----------------
__global__ __launch_bounds__(256) void hist_kernel(
    const int* __restrict__ topIdx, int* __restrict__ cnt, float* __restrict__ y)
{
    __shared__ int lcnt[N_EXP];
    int tid = threadIdx.x;
    if (tid < N_EXP) lcnt[tid] = 0;
    __syncthreads();
    int row = blockIdx.x * 256 + tid;
    y[row] = 0.f;
    int2 e = ((const int2*)topIdx)[row];
    atomicAdd(&lcnt[e.x], 1);
    atomicAdd(&lcnt[e.y], 1);
    __syncthreads();
    if (tid < N_EXP) atomicAdd(&cnt[tid * CNT_STRIDE], lcnt[tid]);
}

// ---------------- 2b. prefix sum to 128-padded per-expert offsets ----------------
__global__ void offsets_kernel(const int* __restrict__ cnt, int* __restrict__ poff)
{
    if (threadIdx.x == 0 && blockIdx.x == 0) {
        int o = 0;
        for (int e = 0; e < N_EXP; ++e) {
            poff[e] = o;
            o += (cnt[e * CNT_STRIDE] + 127) & ~127;
        }
        poff[N_EXP] = o;
    }
}

// ---------------- 3. scatter rows into compact per-expert lists + pad-slot init ----------------
__global__ __launch_bounds__(256) void scatter_kernel(
    const int* __restrict__ topIdx, const float* __restrict__ topGate,
    const int* __restrict__ cnt, const int* __restrict__ poff, int* __restrict__ cnt2,
    int* __restrict__ pairRowC, float* __restrict__ pairGateC)
{
    int tid = threadIdx.x;
    int b = blockIdx.x;

    {   // pad-slot init (all CAP slots covered; padding & real slots disjoint)
        int p = b * 256 + tid;
        int e = 0;
        while (e < N_EXP - 1 && p >= poff[e + 1]) ++e;
        if (p - poff[e] >= cnt[e * CNT_STRIDE]) {
            pairRowC[p] = B_ROWS;      // zero row of xbf
            pairGateC[p] = 0.f;
        }
    }
    if (b >= B_ROWS / 256) return;

    __shared__ int lcnt[N_EXP];
    __shared__ int base[N_EXP];
    if (tid < N_EXP) lcnt[tid] = 0;
    __syncthreads();
    int row = b * 256 + tid;
    int2 e = ((const int2*)topIdx)[row];
    float2 g = ((const float2*)topGate)[row];
    int s0 = atomicAdd(&lcnt[e.x], 1);
    int s1 = atomicAdd(&lcnt[e.y], 1);
    __syncthreads();
    if (tid < N_EXP) base[tid] = atomicAdd(&cnt2[tid * CNT_STRIDE], lcnt[tid]);
    __syncthreads();
    int p0 = poff[e.x] + base[e.x] + s0;
    pairRowC[p0] = row; pairGateC[p0] = g.x;
    int p1 = poff[e.y] + base[e.y] + s1;
    pairRowC[p1] = row; pairGateC[p1] = g.y;
}

// ---------------- 4. expert GEMM: A indirect from xbf, XCD-aware tile mapping ----------------
__global__ __launch_bounds__(256) void gemm_kernel(
    const __hip_bfloat16* __restrict__ xbf, const __hip_bfloat16* __restrict__ w1t,
    const float* __restrict__ b1, const int* __restrict__ poff,
    const int* __restrict__ pairRowC,
    __hip_bfloat16* __restrict__ hbuf)
{
    int bi = blockIdx.x;
    int xcd = bi & 7;
    int j = bi >> 3;                 // [0, 264)
    int col0 = (j & 7) << 7;
    int rt = xcd * 33 + (j >> 3);    // [0, 264)
    int row0 = rt << 7;
    if (row0 >= poff[N_EXP]) return;
    int e = 0;
    while (e < N_EXP - 1 && row0 >= poff[e + 1]) ++e;

    __shared__ short lA[128 * 32];   // seg XOR-swizzled by (row>>1)&3
    __shared__ short lB[128 * 32];

    int t = threadIdx.x;
    int lane = t & 63, w = t >> 6;
    int wm = (w >> 1) * 64, wn = (w & 1) * 64;
    int l15 = lane & 15, quad = lane >> 4;
    int qsw = quad ^ ((l15 >> 1) & 3);

    f32x4 acc[4][4];
#pragma unroll
    for (int i = 0; i < 4; ++i)
#pragma unroll
        for (int j2 = 0; j2 < 4; ++j2) acc[i][j2] = (f32x4){0.f, 0.f, 0.f, 0.f};

    int r1 = t >> 2, seg = t & 3;
    int sw = seg ^ ((r1 >> 1) & 3);
    int ridx1 = pairRowC[row0 + r1];
    int ridx2 = pairRowC[row0 + 64 + r1];
    const __hip_bfloat16* Arow1 = xbf + (long)ridx1 * D_PAD + sw * 8;
    const __hip_bfloat16* Arow2 = xbf + (long)ridx2 * D_PAD + sw * 8;
    const __hip_bfloat16* Bb = w1t + (long)e * H_DIM * D_PAD + (long)col0 * D_PAD;
    const __hip_bfloat16* Brow1 = Bb + (long)r1 * D_PAD + sw * 8;
    const __hip_bfloat16* Brow2 = Bb + (long)(r1 + 64) * D_PAD + sw * 8;
    char* lAc = (char*)lA;
    char* lBc = (char*)lB;

    for (int kt = 0; kt < D_PAD / 32; ++kt) {
        __syncthreads();
        int k0 = kt * 32;
        load_lds16(Arow1 + k0, lAc + t * 16);
        load_lds16(Arow2 + k0, lAc + t * 16 + 4096);
        load_lds16(Brow1 + k0, lBc + t * 16);
        load_lds16(Brow2 + k0, lBc + t * 16 + 4096);
        __syncthreads();

        bf16x8 af[4], bfr[4];
#pragma unroll
        for (int i = 0; i < 4; ++i)
            af[i] = *(const bf16x8*)(lAc + (wm + i * 16 + l15) * 64 + qsw * 16);
#pragma unroll
        for (int j2 = 0; j2 < 4; ++j2)
            bfr[j2] = *(const bf16x8*)(lBc + (wn + j2 * 16 + l15) * 64 + qsw * 16);
#pragma unroll
        for (int i = 0; i < 4; ++i)
#pragma unroll
            for (int j2 = 0; j2 < 4; ++j2)
                acc[i][j2] = __builtin_amdgcn_mfma_f32_16x16x32_bf16(af[i], bfr[j2], acc[i][j2], 0, 0, 0);
    }

#pragma unroll
    for (int i = 0; i < 4; ++i) {
        int lr = wm + i * 16 + quad * 4;
#pragma unroll
        for (int j2 = 0; j2 < 4; ++j2) {
            int gc = col0 + wn + j2 * 16 + l15;
            float bias = b1[e * H_DIM + gc];
#pragma unroll
            for (int r = 0; r < 4; ++r) {
                float v = acc[i][j2][r] + bias;
                hbuf[(long)(row0 + lr + r) * H_DIM + gc] = __float2bfloat16(v);
            }
        }
    }
}

// ---------------- 5. LayerNorm + ReLU + head dot + sigmoid + gated combine ----------------
__global__ __launch_bounds__(256) void ln_head_kernel(
    const __hip_bfloat16* __restrict__ hbuf, const int* __restrict__ cnt, const int* __restrict__ poff,
    const int* __restrict__ pairRowC, const float* __restrict__ pairGateC,
    const float* __restrict__ g1, const float* __restrict__ be1,
    const float* __restrict__ W2, const float* __restrict__ b2,
    float* __restrict__ y)
{
    int p = blockIdx.x;
    if (p >= poff[N_EXP]) return;
    int e = 0;
    while (e < N_EXP - 1 && p >= poff[e + 1]) ++e;
    if (p - poff[e] >= cnt[e * CNT_STRIDE]) return;

    int row = pairRowC[p];
    float gate = pairGateC[p];
    int tid = threadIdx.x;
    int w = tid >> 6;
    const __hip_bfloat16* hr = hbuf + (long)p * H_DIM;

    union { short4v s; __hip_bfloat16 h[4]; } hv;
    hv.s = ((const short4v*)hr)[tid];
    float v[4];
    float sum = 0.f, sumsq = 0.f;
#pragma unroll
    for (int k = 0; k < 4; ++k) {
        v[k] = __bfloat162float(hv.h[k]);
        sum += v[k];
        sumsq += v[k] * v[k];
    }
#pragma unroll
    for (int off = 32; off > 0; off >>= 1) {
        sum += __shfl_down(sum, off);
        sumsq += __shfl_down(sumsq, off);
    }
    __shared__ float rs[4], rq[4];
    if ((tid & 63) == 0) { rs[w] = sum; rq[w] = sumsq; }
    __syncthreads();
    float tot = rs[0] + rs[1] + rs[2] + rs[3];
    float totq = rq[0] + rq[1] + rq[2] + rq[3];
    float mu = tot * (1.f / H_DIM);
    float var = totq * (1.f / H_DIM) - mu * mu;
    float rstd = rsqrtf(var + LN_EPS);

    float4 gv = ((const float4*)(g1 + e * H_DIM))[tid];
    float4 bv = ((const float4*)(be1 + e * H_DIM))[tid];
    float4 wv = ((const float4*)(W2 + e * H_DIM))[tid];
    float z;
    {
        float hn0 = fmaxf((v[0] - mu) * rstd * gv.x + bv.x, 0.f);
        float hn1 = fmaxf((v[1] - mu) * rstd * gv.y + bv.y, 0.f);
        float hn2 = fmaxf((v[2] - mu) * rstd * gv.z + bv.z, 0.f);
        float hn3 = fmaxf((v[3] - mu) * rstd * gv.w + bv.w, 0.f);
        z = hn0 * wv.x + hn1 * wv.y + hn2 * wv.z + hn3 * wv.w;
    }
#pragma unroll
    for (int off = 32; off > 0; off >>= 1) z += __shfl_down(z, off);
    __syncthreads();
    if ((tid & 63) == 0) rs[w] = z;
    __syncthreads();
    if (tid == 0) {
        float zt = rs[0] + rs[1] + rs[2] + rs[3] + b2[e];
        float o = 1.f / (1.f + expf(-zt));
        atomicAdd(&y[row], gate * o);
    }
}

extern "C" void kernel_launch(void* const* d_in, const int* in_sizes, int n_in,
                              void* d_out, int out_size, void* d_ws, size_t ws_size,
                              hipStream_t stream)
{
    const float* x   = (const float*)d_in[0];
    const float* wg  = (const float*)d_in[1];
    const float* W1  = (const float*)d_in[2];
    const float* b1  = (const float*)d_in[3];
    const float* g1  = (const float*)d_in[4];
    const float* be1 = (const float*)d_in[5];
    const float* W2  = (const float*)d_in[6];
    const float* b2  = (const float*)d_in[7];
    float* y = (float*)d_out;

    char* ws = (char*)d_ws;
    int*   cnt       = (int*)(ws + O_CNT);
    int*   poff      = (int*)(ws + O_POFF);
    int*   cnt2      = (int*)(ws + O_CNT2);
    int*   topIdx    = (int*)(ws + O_TOPI);
    float* topGate   = (float*)(ws + O_TOPG);
    int*   pairRowC  = (int*)(ws + O_PROWC);
    float* pairGateC = (float*)(ws + O_PGATEC);
    __hip_bfloat16* xbf  = (__hip_bfloat16*)(ws + O_XBF);
    __hip_bfloat16* w1t  = (__hip_bfloat16*)(ws + O_W1T);
    __hip_bfloat16* hbuf = (__hip_bfloat16*)(ws + O_HBUF);

    hipMemsetAsync(ws, 0, 1088, stream);   // cnt + poff + cnt2

    gating_w1t_kernel<<<GATING_BLOCKS + 1 + W1T_BLOCKS, 256, 0, stream>>>(
        x, wg, W1, topIdx, topGate, w1t, xbf);
    hist_kernel<<<B_ROWS / 256, 256, 0, stream>>>(topIdx, cnt, y);
    offsets_kernel<<<1, 64, 0, stream>>>(cnt, poff);
    scatter_kernel<<<CAP / 256, 256, 0, stream>>>(topIdx, topGate, cnt, poff, cnt2,
                                                  pairRowC, pairGateC);
    gemm_kernel<<<N_TILES * 8, 256, 0, stream>>>(xbf, w1t, b1, poff, pairRowC, hbuf);
    ln_head_kernel<<<CAP, 256, 0, stream>>>(hbuf, cnt, poff, pairRowC, pairGateC,
                                            g1, be1, W2, b2, y);
}